// Round 7
// baseline (3739.056 us; speedup 1.0000x reference)
//
#include <hip/hip_runtime.h>
#include <stdint.h>

typedef unsigned short u16;
typedef unsigned long long u64;
typedef __attribute__((ext_vector_type(8))) short short8;
typedef __attribute__((ext_vector_type(4))) float f32x4;

// ---------------- device-global blob ----------------
#define SZ_BIGW    (4096ull*1024ull*2ull)          // [4096x1024] bf16, fragment-tiled
#define OFF_WHH1   (0ull)
#define OFF_WIH2   (OFF_WHH1 + SZ_BIGW)
#define OFF_WHH2   (OFF_WIH2 + SZ_BIGW)
#define OFF_WIH3   (OFF_WHH2 + SZ_BIGW)
#define OFF_WHH3   (OFF_WIH3 + SZ_BIGW)
#define OFF_MCOMB  (OFF_WHH3 + SZ_BIGW)            // W_ih1 @ W_dec  [4096x1024]
#define OFF_WIH1   (OFF_MCOMB + SZ_BIGW)           // [4096 x 160(pad of 132)]
#define SZ_WIH1    (4096ull*160ull*2ull)
#define OFF_WDECF  (OFF_WIH1 + SZ_WIH1)            // W_dec as B-op, rows f(pad160) x K=1024
#define SZ_WDECF   (160ull*1024ull*2ull)
#define OFF_WDECB  (OFF_WDECF + SZ_WDECF)          // W_dec^T as B-op, rows k(1024) x f(pad160)
#define SZ_WDECB   (1024ull*160ull*2ull)
#define OFF_XPRIM  (OFF_WDECB + SZ_WDECB)          // [64 t][20 kc][32 b][8] bf16
#define SZ_XPRIM   (64ull*5120ull*2ull)
#define OFF_H2HIST (OFF_XPRIM + SZ_XPRIM)          // 129 slots (A-layout), slot0 = prime t=63
#define SZ_HSLOT   (32768ull*2ull)                 // 64 KB per h slot
#define SZ_H2HIST  (129ull*SZ_HSLOT)
#define OFF_H0R    (OFF_H2HIST + SZ_H2HIST)        // write-once ring, depth 192
#define SZ_HR      (192ull*SZ_HSLOT)
#define OFF_H1R    (OFF_H0R + SZ_HR)
#define OFF_H2R    (OFF_H1R + SZ_HR)               // prime-phase ring, depth 64
#define SZ_H2R     (64ull*SZ_HSLOT)
#define OFF_ZEROH  (OFF_H2R + SZ_H2R)              // one zero h slot (t=0 segB input)
#define OFF_FLAGS  (OFF_ZEROH + SZ_HSLOT)          // 3 x 256 u32 flags (3072 B used)
#define SZ_FLAGS   (4096ull)
#define OFF_BS1    (OFF_FLAGS + SZ_FLAGS)          // bias sums fp32 [4096] x4
#define OFF_BS1G   (OFF_BS1 + 16384ull)
#define OFF_BS2    (OFF_BS1G + 16384ull)
#define OFF_BS3    (OFF_BS2 + 16384ull)
#define BLOB_SIZE  (OFF_BS3 + 16384ull)

__device__ unsigned char g_blob[BLOB_SIZE];

// zero region: ZEROH + FLAGS, contiguous
#define ZERO_BYTES (SZ_HSLOT + SZ_FLAGS)

__device__ __forceinline__ u16 f2bf(float f) {
  unsigned u = __float_as_uint(f);
  u += 0x7fffu + ((u >> 16) & 1u);
  return (u16)(u >> 16);
}
__device__ __forceinline__ float sigm(float x) { return 1.f / (1.f + __expf(-x)); }
__device__ __forceinline__ float tanh_(float x) {
  x = fminf(fmaxf(x, -40.f), 40.f);
  float e = __expf(2.f * x);
  return (e - 1.f) / (e + 1.f);
}
__device__ __forceinline__ unsigned umin_(unsigned a, unsigned b) { return a < b ? a : b; }

// ---------------- prep kernels ----------------
__global__ __launch_bounds__(256) void k_zero(uint4* p, int n) {
  int i = blockIdx.x * 256 + threadIdx.x;
  for (; i < n; i += gridDim.x * 256) p[i] = make_uint4(0u, 0u, 0u, 0u);
}

// fragment-tiled layout: dst[(nt*nkc + kc)*128 + jr*8 + ke]
// perm=0: j = nt*16 + jr ; perm=1: j = (jr>>2)*1024 + nt*4 + (jr&3)  (4 h x 4 gates per tile)
__global__ __launch_bounds__(256) void k_swizzle(const float* __restrict__ src, u16* __restrict__ dst,
                                                 int J, int Jsrc, int Kpad, int Ksrc, int srcld,
                                                 int transposed, int perm) {
  int total = J * Kpad;
  int nkc = Kpad >> 3;
  for (int o = blockIdx.x * 256 + threadIdx.x; o < total; o += gridDim.x * 256) {
    int chunk = o >> 7, within = o & 127;
    int nt = chunk / nkc, kc = chunk - nt * nkc;
    int jr = within >> 3, ke = within & 7;
    int j = perm ? ((jr >> 2) * 1024 + nt * 4 + (jr & 3)) : (nt * 16 + jr);
    int k = kc * 8 + ke;
    float v = 0.f;
    if (j < Jsrc && k < Ksrc)
      v = transposed ? src[(size_t)k * srcld + j] : src[(size_t)j * srcld + k];
    dst[o] = f2bf(v);
  }
}

__global__ __launch_bounds__(256) void k_xprim(const float* __restrict__ iseq, u16* __restrict__ dst) {
  int o = blockIdx.x * 256 + threadIdx.x;
  if (o >= 64 * 5120) return;
  int t = o / 5120, rem = o - t * 5120;
  int kc = rem >> 8, b = (rem >> 3) & 31, ke = rem & 7;
  int k = kc * 8 + ke;
  float v = (k < 132) ? iseq[(size_t)b * (64 * 132) + t * 132 + k] : 0.f;
  dst[o] = f2bf(v);
}

__global__ __launch_bounds__(256) void k_bias(const float* bih1, const float* bhh1,
                                              const float* bih2, const float* bhh2,
                                              const float* bih3, const float* bhh3,
                                              const float* __restrict__ Wih1, const float* __restrict__ bdec,
                                              float* bs1, float* bs1g, float* bs2, float* bs3) {
  int j = blockIdx.x * 256 + threadIdx.x;
  if (j >= 4096) return;
  float s1 = bih1[j] + bhh1[j];
  float bc = 0.f;
  const float* wr = Wih1 + (size_t)j * 132;
  for (int f = 0; f < 132; ++f) bc += wr[f] * bdec[f];
  bs1[j] = s1;
  bs1g[j] = s1 + bc;
  bs2[j] = bih2[j] + bhh2[j];
  bs3[j] = bih3[j] + bhh3[j];
}

// Mcomb[j][k] = sum_f Wih1[j][f]*Wdec[f][k]; A-rows and C-rows permute identically.
__global__ __launch_bounds__(256) void k_mcomb(const u16* __restrict__ A, const u16* __restrict__ Bm,
                                               u16* __restrict__ dst) {
  int blk = blockIdx.x;                   // 4096 = 256 mt x 16 jg
  int mt = blk & 255, jg = blk >> 8;
  int w = threadIdx.x >> 6, l = threadIdx.x & 63, q = l >> 4, r = l & 15;
  int nt = jg * 4 + w;
  f32x4 acc = {};
  for (int ks = 0; ks < 5; ++ks) {
    short8 a = *(const short8*)(A + ((size_t)mt * 20 + ks * 4 + q) * 128 + r * 8);
    short8 b = *(const short8*)(Bm + ((size_t)nt * 20 + ks * 4 + q) * 128 + r * 8);
    acc = __builtin_amdgcn_mfma_f32_16x16x32_bf16(a, b, acc, 0, 0, 0);
  }
  int kout = nt * 16 + r;
#pragma unroll
  for (int i = 0; i < 4; ++i) {
    int jrow = q * 4 + i;
    dst[(((size_t)mt * 128 + (kout >> 3)) << 7) + jrow * 8 + (kout & 7)] = f2bf(acc[i]);
  }
}

// ---------------- persistent RNN kernel ----------------
// EXACT round-3 compute/sync structure (best verified: 2370 us, VGPR 52).
// Round-7 additions (numerics-inert):
//  (1) prime-L1 waits F3>=t (closes prime-phase h2 visibility race);
//  (2) in-lull L2 warming: threads 0-255 issue TWO 4-B loads touching the 256
//      cache lines of the NEXT link's two weight tiles; results fold into a
//      dead min-accumulator (stored only under an impossible blockIdx guard).
//      Loads issue before segB, drain during the spin-wait -> next link's
//      weight fetch hits warm L2.

__device__ __forceinline__ void wait_all(unsigned* F, unsigned tgt) {
  if (threadIdx.x < 256) {
    while (__hip_atomic_load(F + threadIdx.x, __ATOMIC_RELAXED, __HIP_MEMORY_SCOPE_AGENT) < tgt)
      __builtin_amdgcn_s_sleep(1);
  }
  __syncthreads();
}

__device__ __forceinline__ void layer_step(
    const u16* __restrict__ xa, const u16* __restrict__ Wa, int nsA, int nkcA,
    const u16* __restrict__ xb, const u16* __restrict__ Wb,
    const u16* __restrict__ pfa, const u16* __restrict__ pfb,   // next link's weight tiles (warm)
    unsigned* waitF, unsigned wtgt,
    const float* __restrict__ bsum, float& creg, u16* __restrict__ hout,
    unsigned* arrF, unsigned aval,
    float (*red)[2][256], u64* hstage, int nt, unsigned& wmin)
{
  int tid = threadIdx.x;
  int w = tid >> 6, l = tid & 63, q = l >> 4, r = l & 15;
  f32x4 acc0 = {}, acc1 = {};

  // ---- L2-warming touches for the next link (one 128B line per thread per tile) ----
  unsigned v0 = 0xFFFFFFFFu, v1 = 0xFFFFFFFFu;
  if (tid < 256) {
    v0 = *((const unsigned*)pfa + tid * 32);
    v1 = *((const unsigned*)pfb + tid * 32);
  }

  // segB: self-recurrent (input ready from prior step via earlier covering wait)
  const u16* wb_base = Wb + (size_t)nt * 128 * 128;
  for (int ks = w; ks < 32; ks += 8) {
    const u16* xp = xb + ks * 1024 + q * 256 + r * 8;
    short8 a0 = *(const short8*)(xp);
    short8 a1 = *(const short8*)(xp + 128);
    short8 bf = *(const short8*)(wb_base + ((size_t)(ks * 4) << 7) + l * 8);
    acc0 = __builtin_amdgcn_mfma_f32_16x16x32_bf16(a0, bf, acc0, 0, 0, 0);
    acc1 = __builtin_amdgcn_mfma_f32_16x16x32_bf16(a1, bf, acc1, 0, 0, 0);
  }

  if (waitF) wait_all(waitF, wtgt);

  // fold warm-load results into dead accumulator (keeps loads; ~free, post-drain)
  if (tid < 256) wmin = umin_(wmin, umin_(v0, v1));

  // segA: cross-layer input
  const u16* wa_base = Wa + (size_t)nt * nkcA * 128;
  for (int ks = w; ks < nsA; ks += 8) {
    const u16* xp = xa + ks * 1024 + q * 256 + r * 8;
    short8 a0 = *(const short8*)(xp);
    short8 a1 = *(const short8*)(xp + 128);
    short8 bf = *(const short8*)(wa_base + ((size_t)(ks * 4) << 7) + l * 8);
    acc0 = __builtin_amdgcn_mfma_f32_16x16x32_bf16(a0, bf, acc0, 0, 0, 0);
    acc1 = __builtin_amdgcn_mfma_f32_16x16x32_bf16(a1, bf, acc1, 0, 0, 0);
  }

  // ---- epilogue: cross-wave reduce, gates, cell update, h publish ----
#pragma unroll
  for (int i = 0; i < 4; ++i) { red[w][0][l * 4 + i] = acc0[i]; red[w][1][l * 4 + i] = acc1[i]; }
  __syncthreads();

  if (tid < 128) {
    int b = tid >> 2, hl = tid & 3;
    int mt = b >> 4, row = b & 15;
    int j0 = nt * 4 + hl;
    float g4[4];
#pragma unroll
    for (int g = 0; g < 4; ++g) {
      int col = g * 4 + hl;
      int lidx = ((row >> 2) * 16 + col) * 4 + (row & 3);
      float s = bsum[g * 1024 + j0];
#pragma unroll
      for (int ww = 0; ww < 8; ++ww) s += red[ww][mt][lidx];
      g4[g] = s;
    }
    float iv = sigm(g4[0]), fv = sigm(g4[1]), gv = tanh_(g4[2]), ov = sigm(g4[3]);
    float cn = fv * creg + iv * gv;
    creg = cn;
    ((u16*)hstage)[tid] = f2bf(ov * tanh_(cn));   // [b][hl]
  }
  __syncthreads();

  // wave 0: 32 u64 agent-scope stores (write-once slot), then flag release
  if (tid < 64) {
    if (tid < 32) {
      u64 v = hstage[tid];
      u64* dp = (u64*)(hout + ((size_t)(nt >> 1) * 256 + tid * 8 + (nt & 1) * 4));
      __hip_atomic_store(dp, v, __ATOMIC_RELAXED, __HIP_MEMORY_SCOPE_AGENT);
    }
    asm volatile("s_waitcnt vmcnt(0)" ::: "memory");
    if (tid == 0)
      __hip_atomic_store(arrF + nt, aval, __ATOMIC_RELAXED, __HIP_MEMORY_SCOPE_AGENT);
  }
}

__global__ __launch_bounds__(512) void k_rnn(unsigned char* blob) {
  __shared__ float red[8][2][256];
  __shared__ u64 hstage[32];
  const u16* XPRIM = (const u16*)(blob + OFF_XPRIM);
  const u16* tWIH1 = (const u16*)(blob + OFF_WIH1);
  const u16* tMCOMB = (const u16*)(blob + OFF_MCOMB);
  const u16* tWHH1 = (const u16*)(blob + OFF_WHH1);
  const u16* tWIH2 = (const u16*)(blob + OFF_WIH2);
  const u16* tWHH2 = (const u16*)(blob + OFF_WHH2);
  const u16* tWIH3 = (const u16*)(blob + OFF_WIH3);
  const u16* tWHH3 = (const u16*)(blob + OFF_WHH3);
  const float* BS1 = (const float*)(blob + OFF_BS1);
  const float* BS1G = (const float*)(blob + OFF_BS1G);
  const float* BS2 = (const float*)(blob + OFF_BS2);
  const float* BS3 = (const float*)(blob + OFF_BS3);
  u16* H0R = (u16*)(blob + OFF_H0R);
  u16* H1R = (u16*)(blob + OFF_H1R);
  u16* H2R = (u16*)(blob + OFF_H2R);
  u16* H2HIST = (u16*)(blob + OFF_H2HIST);
  const u16* ZEROH = (const u16*)(blob + OFF_ZEROH);
  unsigned* FLAGS = (unsigned*)(blob + OFF_FLAGS);
  unsigned *F1 = FLAGS, *F2 = FLAGS + 256, *F3 = FLAGS + 512;

  int nt = blockIdx.x;
  // per-block warm-target tile bases
  const u16* pWIH1 = tWIH1 + (size_t)nt * 20 * 128;
  const u16* pMCOMB = tMCOMB + (size_t)nt * 128 * 128;
  const u16* pWHH1 = tWHH1 + (size_t)nt * 128 * 128;
  const u16* pWIH2 = tWIH2 + (size_t)nt * 128 * 128;
  const u16* pWHH2 = tWHH2 + (size_t)nt * 128 * 128;
  const u16* pWIH3 = tWIH3 + (size_t)nt * 128 * 128;
  const u16* pWHH3 = tWHH3 + (size_t)nt * 128 * 128;

  float c0r = 0.f, c1r = 0.f, c2r = 0.f;
  unsigned wmin = 0xFFFFFFFFu;

  // ---- priming phase ----
  for (int t = 0; t < 64; ++t) {
    const u16* h0prev = (t == 0) ? ZEROH : H0R + (size_t)(t - 1) * 32768;
    layer_step(XPRIM + t * 5120, tWIH1, 5, 20, h0prev, tWHH1,
               pWIH2, pWHH2,
               F3, (unsigned)t,
               BS1, c0r, H0R + (size_t)t * 32768,
               F1, (unsigned)(t + 1), red, hstage, nt, wmin);
    const u16* h1prev = (t == 0) ? ZEROH : H1R + (size_t)(t - 1) * 32768;
    layer_step(H0R + (size_t)t * 32768, tWIH2, 32, 128, h1prev, tWHH2,
               pWIH3, pWHH3,
               F1, (unsigned)(t + 1),
               BS2, c1r, H1R + (size_t)t * 32768,
               F2, (unsigned)(t + 1), red, hstage, nt, wmin);
    const u16* h2prev = (t == 0) ? ZEROH : H2R + (size_t)(t - 1) * 32768;
    u16* h2out = (t < 63) ? H2R + (size_t)t * 32768 : H2HIST;
    layer_step(H1R + (size_t)t * 32768, tWIH3, 32, 128, h2prev, tWHH3,
               (t < 63) ? pWIH1 : pMCOMB, pWHH1,
               F2, (unsigned)(t + 1),
               BS3, c2r, h2out,
               F3, (unsigned)(t + 1), red, hstage, nt, wmin);
  }
  // ---- generation phase ----
  for (int t = 64; t < 192; ++t) {
    layer_step(H2HIST + (size_t)(t - 64) * 32768, tMCOMB, 32, 128,
               H0R + (size_t)(t - 1) * 32768, tWHH1,
               pWIH2, pWHH2,
               F3, (unsigned)t,
               BS1G, c0r, H0R + (size_t)t * 32768,
               F1, (unsigned)(t + 1), red, hstage, nt, wmin);
    layer_step(H0R + (size_t)t * 32768, tWIH2, 32, 128,
               H1R + (size_t)(t - 1) * 32768, tWHH2,
               pWIH3, pWHH3,
               F1, (unsigned)(t + 1),
               BS2, c1r, H1R + (size_t)t * 32768,
               F2, (unsigned)(t + 1), red, hstage, nt, wmin);
    layer_step(H1R + (size_t)t * 32768, tWIH3, 32, 128,
               H2HIST + (size_t)(t - 64) * 32768, tWHH3,
               pMCOMB, pWHH1,
               F2, (unsigned)(t + 1),
               BS3, c2r, H2HIST + (size_t)(t - 63) * 32768,
               F3, (unsigned)(t + 1), red, hstage, nt, wmin);
  }
  // dead sink: keeps warm loads alive; never executes (gridDim is 256)
  if (nt == 0x77777777) ((volatile unsigned*)(blob + OFF_FLAGS + 3584))[threadIdx.x & 63] = wmin;
}

// ---------------- batched decoder over all 128 generated h2 states ----------------
__global__ __launch_bounds__(256) void k_dec(const u16* __restrict__ h2hist, const u16* __restrict__ Wd,
                                             const float* __restrict__ bdec, float* __restrict__ out) {
  int blk = blockIdx.x;
  int s = blk / 10, nt = blk - s * 10;
  const u16* x = h2hist + (size_t)(s + 1) * 32768;
  int w = threadIdx.x >> 6, l = threadIdx.x & 63, q = l >> 4, r = l & 15;
  f32x4 acc[2] = {};
  for (int ks = w; ks < 32; ks += 4) {
    const u16* xp = x + ks * 1024 + q * 256 + r * 8;
    short8 a0 = *(const short8*)(xp);
    short8 a1 = *(const short8*)(xp + 128);
    short8 bf = *(const short8*)(Wd + (((size_t)nt * 128 + ks * 4) << 7) + l * 8);
    acc[0] = __builtin_amdgcn_mfma_f32_16x16x32_bf16(a0, bf, acc[0], 0, 0, 0);
    acc[1] = __builtin_amdgcn_mfma_f32_16x16x32_bf16(a1, bf, acc[1], 0, 0, 0);
  }
  __shared__ float red[4][2][256];
#pragma unroll
  for (int mt = 0; mt < 2; ++mt)
#pragma unroll
    for (int i = 0; i < 4; ++i) red[w][mt][l * 4 + i] = acc[mt][i];
  __syncthreads();
  for (int pp = threadIdx.x; pp < 512; pp += 256) {
    int b = pp >> 4, fs = pp & 15;
    int mt = b >> 4, row = b & 15;
    int lidx = ((row >> 2) * 16 + fs) * 4 + (row & 3);
    int f = nt * 16 + fs;
    if (f < 132) {
      float v = red[0][mt][lidx] + red[1][mt][lidx] + red[2][mt][lidx] + red[3][mt][lidx] + bdec[f];
      out[(size_t)b * (128 * 132) + s * 132 + f] = v;
    }
  }
}

// ---------------- host ----------------
extern "C" void kernel_launch(void* const* d_in, const int* in_sizes, int n_in,
                              void* d_out, int out_size, void* d_ws, size_t ws_size,
                              hipStream_t stream) {
  unsigned char* blob = nullptr;
  hipGetSymbolAddress((void**)&blob, HIP_SYMBOL(g_blob));

  const float* iseq = (const float*)d_in[0];
  const float* Wih1 = (const float*)d_in[2];
  const float* Whh1 = (const float*)d_in[3];
  const float* bih1 = (const float*)d_in[4];
  const float* bhh1 = (const float*)d_in[5];
  const float* Wih2 = (const float*)d_in[6];
  const float* Whh2 = (const float*)d_in[7];
  const float* bih2 = (const float*)d_in[8];
  const float* bhh2 = (const float*)d_in[9];
  const float* Wih3 = (const float*)d_in[10];
  const float* Whh3 = (const float*)d_in[11];
  const float* bih3 = (const float*)d_in[12];
  const float* bhh3 = (const float*)d_in[13];
  const float* Wdec = (const float*)d_in[14];
  const float* bdec = (const float*)d_in[15];

  u16* tWHH1 = (u16*)(blob + OFF_WHH1);
  u16* tWIH2 = (u16*)(blob + OFF_WIH2);
  u16* tWHH2 = (u16*)(blob + OFF_WHH2);
  u16* tWIH3 = (u16*)(blob + OFF_WIH3);
  u16* tWHH3 = (u16*)(blob + OFF_WHH3);
  u16* tMCOMB = (u16*)(blob + OFF_MCOMB);
  u16* tWIH1 = (u16*)(blob + OFF_WIH1);
  u16* tWDECF = (u16*)(blob + OFF_WDECF);
  u16* tWDECB = (u16*)(blob + OFF_WDECB);
  u16* XPRIM = (u16*)(blob + OFF_XPRIM);
  u16* H2HIST = (u16*)(blob + OFF_H2HIST);
  float* BS1 = (float*)(blob + OFF_BS1);
  float* BS1G = (float*)(blob + OFF_BS1G);
  float* BS2 = (float*)(blob + OFF_BS2);
  float* BS3 = (float*)(blob + OFF_BS3);

  // prep
  k_zero<<<68, 256, 0, stream>>>((uint4*)(blob + OFF_ZEROH), (int)(ZERO_BYTES / 16));
  k_swizzle<<<2048, 256, 0, stream>>>(Whh1, tWHH1, 4096, 4096, 1024, 1024, 1024, 0, 1);
  k_swizzle<<<2048, 256, 0, stream>>>(Wih2, tWIH2, 4096, 4096, 1024, 1024, 1024, 0, 1);
  k_swizzle<<<2048, 256, 0, stream>>>(Whh2, tWHH2, 4096, 4096, 1024, 1024, 1024, 0, 1);
  k_swizzle<<<2048, 256, 0, stream>>>(Wih3, tWIH3, 4096, 4096, 1024, 1024, 1024, 0, 1);
  k_swizzle<<<2048, 256, 0, stream>>>(Whh3, tWHH3, 4096, 4096, 1024, 1024, 1024, 0, 1);
  k_swizzle<<<2048, 256, 0, stream>>>(Wih1, tWIH1, 4096, 4096, 160, 132, 132, 0, 1);
  k_swizzle<<<512, 256, 0, stream>>>(Wdec, tWDECF, 160, 132, 1024, 1024, 1024, 0, 0);
  k_swizzle<<<512, 256, 0, stream>>>(Wdec, tWDECB, 1024, 1024, 160, 132, 1024, 1, 0);
  k_xprim<<<1280, 256, 0, stream>>>(iseq, XPRIM);
  k_bias<<<16, 256, 0, stream>>>(bih1, bhh1, bih2, bhh2, bih3, bhh3, Wih1, bdec, BS1, BS1G, BS2, BS3);
  k_mcomb<<<4096, 256, 0, stream>>>(tWIH1, tWDECB, tMCOMB);

  // persistent RNN
  {
    void* args[] = { (void*)&blob };
    hipError_t ce = hipLaunchCooperativeKernel((void*)k_rnn, dim3(256), dim3(512), args, 0, stream);
    if (ce != hipSuccess) {
      k_rnn<<<dim3(256), dim3(512), 0, stream>>>(blob);
    }
  }

  // batched decoder -> d_out fp32 [32][128][132]
  k_dec<<<1280, 256, 0, stream>>>(H2HIST, tWDECF, bdec, (float*)d_out);
}

// Round 8
// 2398.404 us; speedup vs baseline: 1.5590x; 1.5590x over previous
//
#include <hip/hip_runtime.h>
#include <stdint.h>

typedef unsigned short u16;
typedef unsigned long long u64;
typedef __attribute__((ext_vector_type(8))) short short8;
typedef __attribute__((ext_vector_type(4))) float f32x4;

// ---------------- device-global blob ----------------
#define SZ_BIGW    (4096ull*1024ull*2ull)          // [4096x1024] bf16, fragment-tiled
#define OFF_WHH1   (0ull)
#define OFF_WIH2   (OFF_WHH1 + SZ_BIGW)
#define OFF_WHH2   (OFF_WIH2 + SZ_BIGW)
#define OFF_WIH3   (OFF_WHH2 + SZ_BIGW)
#define OFF_WHH3   (OFF_WIH3 + SZ_BIGW)
#define OFF_MCOMB  (OFF_WHH3 + SZ_BIGW)            // W_ih1 @ W_dec  [4096x1024]
#define OFF_WIH1   (OFF_MCOMB + SZ_BIGW)           // [4096 x 160(pad of 132)]
#define SZ_WIH1    (4096ull*160ull*2ull)
#define OFF_WDECF  (OFF_WIH1 + SZ_WIH1)            // W_dec as B-op, rows f(pad160) x K=1024
#define SZ_WDECF   (160ull*1024ull*2ull)
#define OFF_WDECB  (OFF_WDECF + SZ_WDECF)          // W_dec^T as B-op, rows k(1024) x f(pad160)
#define SZ_WDECB   (1024ull*160ull*2ull)
#define OFF_XPRIM  (OFF_WDECB + SZ_WDECB)          // [64 t][20 kc][32 b][8] bf16
#define SZ_XPRIM   (64ull*5120ull*2ull)
#define OFF_H2HIST (OFF_XPRIM + SZ_XPRIM)          // 129 slots (A-layout), slot0 = prime t=63
#define SZ_HSLOT   (32768ull*2ull)                 // 64 KB per h slot
#define SZ_H2HIST  (129ull*SZ_HSLOT)
#define OFF_H0R    (OFF_H2HIST + SZ_H2HIST)        // write-once ring, depth 192
#define SZ_HR      (192ull*SZ_HSLOT)
#define OFF_H1R    (OFF_H0R + SZ_HR)
#define OFF_H2R    (OFF_H1R + SZ_HR)               // prime-phase ring, depth 64
#define SZ_H2R     (64ull*SZ_HSLOT)
#define OFF_ZEROH  (OFF_H2R + SZ_H2R)              // one zero h slot (t=0 segB input)
#define OFF_FLAGS  (OFF_ZEROH + SZ_HSLOT)          // 3 x 256 u32 flags (3072 B used)
#define SZ_FLAGS   (4096ull)
#define OFF_BS1    (OFF_FLAGS + SZ_FLAGS)          // bias sums fp32 [4096] x4
#define OFF_BS1G   (OFF_BS1 + 16384ull)
#define OFF_BS2    (OFF_BS1G + 16384ull)
#define OFF_BS3    (OFF_BS2 + 16384ull)
#define BLOB_SIZE  (OFF_BS3 + 16384ull)

__device__ unsigned char g_blob[BLOB_SIZE];

// zero region: ZEROH + FLAGS, contiguous
#define ZERO_BYTES (SZ_HSLOT + SZ_FLAGS)

__device__ __forceinline__ u16 f2bf(float f) {
  unsigned u = __float_as_uint(f);
  u += 0x7fffu + ((u >> 16) & 1u);
  return (u16)(u >> 16);
}
__device__ __forceinline__ float sigm(float x) { return 1.f / (1.f + __expf(-x)); }
__device__ __forceinline__ float tanh_(float x) {
  x = fminf(fmaxf(x, -40.f), 40.f);
  float e = __expf(2.f * x);
  return (e - 1.f) / (e + 1.f);
}

// ---------------- prep kernels ----------------
__global__ __launch_bounds__(256) void k_zero(uint4* p, int n) {
  int i = blockIdx.x * 256 + threadIdx.x;
  for (; i < n; i += gridDim.x * 256) p[i] = make_uint4(0u, 0u, 0u, 0u);
}

// fragment-tiled layout: dst[(nt*nkc + kc)*128 + jr*8 + ke]
// perm=0: j = nt*16 + jr ; perm=1: j = (jr>>2)*1024 + nt*4 + (jr&3)  (4 h x 4 gates per tile)
__global__ __launch_bounds__(256) void k_swizzle(const float* __restrict__ src, u16* __restrict__ dst,
                                                 int J, int Jsrc, int Kpad, int Ksrc, int srcld,
                                                 int transposed, int perm) {
  int total = J * Kpad;
  int nkc = Kpad >> 3;
  for (int o = blockIdx.x * 256 + threadIdx.x; o < total; o += gridDim.x * 256) {
    int chunk = o >> 7, within = o & 127;
    int nt = chunk / nkc, kc = chunk - nt * nkc;
    int jr = within >> 3, ke = within & 7;
    int j = perm ? ((jr >> 2) * 1024 + nt * 4 + (jr & 3)) : (nt * 16 + jr);
    int k = kc * 8 + ke;
    float v = 0.f;
    if (j < Jsrc && k < Ksrc)
      v = transposed ? src[(size_t)k * srcld + j] : src[(size_t)j * srcld + k];
    dst[o] = f2bf(v);
  }
}

__global__ __launch_bounds__(256) void k_xprim(const float* __restrict__ iseq, u16* __restrict__ dst) {
  int o = blockIdx.x * 256 + threadIdx.x;
  if (o >= 64 * 5120) return;
  int t = o / 5120, rem = o - t * 5120;
  int kc = rem >> 8, b = (rem >> 3) & 31, ke = rem & 7;
  int k = kc * 8 + ke;
  float v = (k < 132) ? iseq[(size_t)b * (64 * 132) + t * 132 + k] : 0.f;
  dst[o] = f2bf(v);
}

__global__ __launch_bounds__(256) void k_bias(const float* bih1, const float* bhh1,
                                              const float* bih2, const float* bhh2,
                                              const float* bih3, const float* bhh3,
                                              const float* __restrict__ Wih1, const float* __restrict__ bdec,
                                              float* bs1, float* bs1g, float* bs2, float* bs3) {
  int j = blockIdx.x * 256 + threadIdx.x;
  if (j >= 4096) return;
  float s1 = bih1[j] + bhh1[j];
  float bc = 0.f;
  const float* wr = Wih1 + (size_t)j * 132;
  for (int f = 0; f < 132; ++f) bc += wr[f] * bdec[f];
  bs1[j] = s1;
  bs1g[j] = s1 + bc;
  bs2[j] = bih2[j] + bhh2[j];
  bs3[j] = bih3[j] + bhh3[j];
}

// Mcomb[j][k] = sum_f Wih1[j][f]*Wdec[f][k]; A-rows and C-rows permute identically.
__global__ __launch_bounds__(256) void k_mcomb(const u16* __restrict__ A, const u16* __restrict__ Bm,
                                               u16* __restrict__ dst) {
  int blk = blockIdx.x;                   // 4096 = 256 mt x 16 jg
  int mt = blk & 255, jg = blk >> 8;
  int w = threadIdx.x >> 6, l = threadIdx.x & 63, q = l >> 4, r = l & 15;
  int nt = jg * 4 + w;
  f32x4 acc = {};
  for (int ks = 0; ks < 5; ++ks) {
    short8 a = *(const short8*)(A + ((size_t)mt * 20 + ks * 4 + q) * 128 + r * 8);
    short8 b = *(const short8*)(Bm + ((size_t)nt * 20 + ks * 4 + q) * 128 + r * 8);
    acc = __builtin_amdgcn_mfma_f32_16x16x32_bf16(a, b, acc, 0, 0, 0);
  }
  int kout = nt * 16 + r;
#pragma unroll
  for (int i = 0; i < 4; ++i) {
    int jrow = q * 4 + i;
    dst[(((size_t)mt * 128 + (kout >> 3)) << 7) + jrow * 8 + (kout & 7)] = f2bf(acc[i]);
  }
}

// ---------------- persistent RNN kernel ----------------
// 256 blocks x 512 threads, 1 block/CU. Block nt owns N-tile nt (4 h x 4 gates).
// R3's verified fence-free sync protocol, unchanged.
// Round-8: (a) WHH1/2/3 weight tiles (96 KB) LDS-RESIDENT — segB never reads
// global weights; (b) segA tile staged through a single 32 KB LDS buffer:
// global loads issued at link start (drain during segB+wait), ds_written after
// the first epilogue barrier (all segA LDS reads complete), consumed by the
// next segA-buffer user. Remaining global weight traffic = segA matrices only
// (3 MB/XCD/step -> L2-resident).

__device__ __forceinline__ void wait_all(unsigned* F, unsigned tgt) {
  if (threadIdx.x < 256) {
    while (__hip_atomic_load(F + threadIdx.x, __ATOMIC_RELAXED, __HIP_MEMORY_SCOPE_AGENT) < tgt)
      __builtin_amdgcn_s_sleep(1);
  }
  __syncthreads();
}

template<bool PRIME>
__device__ __forceinline__ void layer_step(
    const u16* __restrict__ xa,            // segA A-input (global)
    const u16* __restrict__ waG,           // PRIME: global WIH1 tile base (else unused)
    const u16* __restrict__ segaL,         // LDS segA weights (non-prime)
    const u16* __restrict__ xb,            // segB A-input (global)
    const u16* __restrict__ wbL,           // LDS resident WHH tile
    const u16* __restrict__ stage_g,       // next segA tile global base (nullable)
    unsigned* waitF, unsigned wtgt,
    const float* __restrict__ bsum, float& creg, u16* __restrict__ hout,
    unsigned* arrF, unsigned aval,
    float (*red)[2][256], u64* hstage, u16* segabuf, int nt)
{
  int tid = threadIdx.x;
  int w = tid >> 6, l = tid & 63, q = l >> 4, r = l & 15;
  f32x4 acc0 = {}, acc1 = {};

  // issue staging loads for the next segA-buffer consumer (drain during segB+wait)
  short8 st[4];
  if (stage_g) {
#pragma unroll
    for (int i = 0; i < 4; ++i)
      st[i] = *(const short8*)(stage_g + i * 4096 + tid * 8);
  }

  // segB: self-recurrent, weights from resident LDS
  for (int ks = w; ks < 32; ks += 8) {
    const u16* xp = xb + ks * 1024 + q * 256 + r * 8;
    short8 a0 = *(const short8*)(xp);
    short8 a1 = *(const short8*)(xp + 128);
    short8 bf = *(const short8*)(wbL + ks * 512 + l * 8);
    acc0 = __builtin_amdgcn_mfma_f32_16x16x32_bf16(a0, bf, acc0, 0, 0, 0);
    acc1 = __builtin_amdgcn_mfma_f32_16x16x32_bf16(a1, bf, acc1, 0, 0, 0);
  }

  if (waitF) wait_all(waitF, wtgt);

  // segA: cross-layer input
  if constexpr (PRIME) {
    for (int ks = w; ks < 5; ks += 8) {
      const u16* xp = xa + ks * 1024 + q * 256 + r * 8;
      short8 a0 = *(const short8*)(xp);
      short8 a1 = *(const short8*)(xp + 128);
      short8 bf = *(const short8*)(waG + ((size_t)(ks * 4) << 7) + l * 8);
      acc0 = __builtin_amdgcn_mfma_f32_16x16x32_bf16(a0, bf, acc0, 0, 0, 0);
      acc1 = __builtin_amdgcn_mfma_f32_16x16x32_bf16(a1, bf, acc1, 0, 0, 0);
    }
  } else {
    for (int ks = w; ks < 32; ks += 8) {
      const u16* xp = xa + ks * 1024 + q * 256 + r * 8;
      short8 a0 = *(const short8*)(xp);
      short8 a1 = *(const short8*)(xp + 128);
      short8 bf = *(const short8*)(segaL + ks * 512 + l * 8);
      acc0 = __builtin_amdgcn_mfma_f32_16x16x32_bf16(a0, bf, acc0, 0, 0, 0);
      acc1 = __builtin_amdgcn_mfma_f32_16x16x32_bf16(a1, bf, acc1, 0, 0, 0);
    }
  }

  // ---- epilogue ----
#pragma unroll
  for (int i = 0; i < 4; ++i) { red[w][0][l * 4 + i] = acc0[i]; red[w][1][l * 4 + i] = acc1[i]; }
  __syncthreads();   // all segA LDS reads complete past this barrier

  // overwrite segA buffer with the staged next tile (safe: post-barrier)
  if (stage_g) {
#pragma unroll
    for (int i = 0; i < 4; ++i)
      *(short8*)(segabuf + i * 4096 + tid * 8) = st[i];
  }

  if (tid < 128) {
    int b = tid >> 2, hl = tid & 3;
    int mt = b >> 4, row = b & 15;
    int j0 = nt * 4 + hl;
    float g4[4];
#pragma unroll
    for (int g = 0; g < 4; ++g) {
      int col = g * 4 + hl;
      int lidx = ((row >> 2) * 16 + col) * 4 + (row & 3);
      float s = bsum[g * 1024 + j0];
#pragma unroll
      for (int ww = 0; ww < 8; ++ww) s += red[ww][mt][lidx];
      g4[g] = s;
    }
    float iv = sigm(g4[0]), fv = sigm(g4[1]), gv = tanh_(g4[2]), ov = sigm(g4[3]);
    float cn = fv * creg + iv * gv;
    creg = cn;
    ((u16*)hstage)[tid] = f2bf(ov * tanh_(cn));   // [b][hl]
  }
  __syncthreads();   // also drains the ds_writes above before next link reads

  // wave 0: 32 u64 agent-scope stores (write-once slot), then flag release
  if (tid < 64) {
    if (tid < 32) {
      u64 v = hstage[tid];
      u64* dp = (u64*)(hout + ((size_t)(nt >> 1) * 256 + tid * 8 + (nt & 1) * 4));
      __hip_atomic_store(dp, v, __ATOMIC_RELAXED, __HIP_MEMORY_SCOPE_AGENT);
    }
    asm volatile("s_waitcnt vmcnt(0)" ::: "memory");
    if (tid == 0)
      __hip_atomic_store(arrF + nt, aval, __ATOMIC_RELAXED, __HIP_MEMORY_SCOPE_AGENT);
  }
}

__global__ __launch_bounds__(512, 1) void k_rnn(unsigned char* blob) {
  __shared__ u16 whhL[3][16384];     // 96 KB resident WHH tiles
  __shared__ u16 segaL[16384];       // 32 KB staged segA tile
  __shared__ float red[8][2][256];   // 16 KB
  __shared__ u64 hstage[32];
  const u16* XPRIM = (const u16*)(blob + OFF_XPRIM);
  const u16* tWIH1 = (const u16*)(blob + OFF_WIH1);
  const u16* tMCOMB = (const u16*)(blob + OFF_MCOMB);
  const u16* tWHH1 = (const u16*)(blob + OFF_WHH1);
  const u16* tWIH2 = (const u16*)(blob + OFF_WIH2);
  const u16* tWHH2 = (const u16*)(blob + OFF_WHH2);
  const u16* tWIH3 = (const u16*)(blob + OFF_WIH3);
  const u16* tWHH3 = (const u16*)(blob + OFF_WHH3);
  const float* BS1 = (const float*)(blob + OFF_BS1);
  const float* BS1G = (const float*)(blob + OFF_BS1G);
  const float* BS2 = (const float*)(blob + OFF_BS2);
  const float* BS3 = (const float*)(blob + OFF_BS3);
  u16* H0R = (u16*)(blob + OFF_H0R);
  u16* H1R = (u16*)(blob + OFF_H1R);
  u16* H2R = (u16*)(blob + OFF_H2R);
  u16* H2HIST = (u16*)(blob + OFF_H2HIST);
  const u16* ZEROH = (const u16*)(blob + OFF_ZEROH);
  unsigned* FLAGS = (unsigned*)(blob + OFF_FLAGS);
  unsigned *F1 = FLAGS, *F2 = FLAGS + 256, *F3 = FLAGS + 512;

  int nt = blockIdx.x;
  int tid = threadIdx.x;
  const u16* gWIH1 = tWIH1 + (size_t)nt * 20 * 128;     // prime L1 segA (global, 5 KB)
  const u16* gMCOMB = tMCOMB + (size_t)nt * 16384;
  const u16* gWIH2 = tWIH2 + (size_t)nt * 16384;
  const u16* gWIH3 = tWIH3 + (size_t)nt * 16384;

  // ---- prologue: load resident WHH tiles + initial WIH2 into LDS ----
  {
    const u16* srcs[4] = { tWHH1 + (size_t)nt * 16384, tWHH2 + (size_t)nt * 16384,
                           tWHH3 + (size_t)nt * 16384, gWIH2 };
    u16* dsts[4] = { whhL[0], whhL[1], whhL[2], segaL };
#pragma unroll
    for (int tt = 0; tt < 4; ++tt)
#pragma unroll
      for (int i = 0; i < 4; ++i)
        *(short8*)(dsts[tt] + i * 4096 + tid * 8) = *(const short8*)(srcs[tt] + i * 4096 + tid * 8);
    __syncthreads();
  }

  float c0r = 0.f, c1r = 0.f, c2r = 0.f;

  // ---- priming phase ----
  for (int t = 0; t < 64; ++t) {
    const u16* h0prev = (t == 0) ? ZEROH : H0R + (size_t)(t - 1) * 32768;
    layer_step<true>(XPRIM + t * 5120, gWIH1, nullptr,
                     h0prev, whhL[0], nullptr,
                     F3, (unsigned)t,
                     BS1, c0r, H0R + (size_t)t * 32768,
                     F1, (unsigned)(t + 1), red, hstage, segaL, nt);
    const u16* h1prev = (t == 0) ? ZEROH : H1R + (size_t)(t - 1) * 32768;
    layer_step<false>(H0R + (size_t)t * 32768, nullptr, segaL,
                      h1prev, whhL[1], gWIH3,
                      F1, (unsigned)(t + 1),
                      BS2, c1r, H1R + (size_t)t * 32768,
                      F2, (unsigned)(t + 1), red, hstage, segaL, nt);
    const u16* h2prev = (t == 0) ? ZEROH : H2R + (size_t)(t - 1) * 32768;
    u16* h2out = (t < 63) ? H2R + (size_t)t * 32768 : H2HIST;
    layer_step<false>(H1R + (size_t)t * 32768, nullptr, segaL,
                      h2prev, whhL[2], (t < 63) ? gWIH2 : gMCOMB,
                      F2, (unsigned)(t + 1),
                      BS3, c2r, h2out,
                      F3, (unsigned)(t + 1), red, hstage, segaL, nt);
  }
  // ---- generation phase ----
  for (int t = 64; t < 192; ++t) {
    layer_step<false>(H2HIST + (size_t)(t - 64) * 32768, nullptr, segaL,
                      H0R + (size_t)(t - 1) * 32768, whhL[0], gWIH2,
                      F3, (unsigned)t,
                      BS1G, c0r, H0R + (size_t)t * 32768,
                      F1, (unsigned)(t + 1), red, hstage, segaL, nt);
    layer_step<false>(H0R + (size_t)t * 32768, nullptr, segaL,
                      H1R + (size_t)(t - 1) * 32768, whhL[1], gWIH3,
                      F1, (unsigned)(t + 1),
                      BS2, c1r, H1R + (size_t)t * 32768,
                      F2, (unsigned)(t + 1), red, hstage, segaL, nt);
    layer_step<false>(H1R + (size_t)t * 32768, nullptr, segaL,
                      H2HIST + (size_t)(t - 64) * 32768, whhL[2], gMCOMB,
                      F2, (unsigned)(t + 1),
                      BS3, c2r, H2HIST + (size_t)(t - 63) * 32768,
                      F3, (unsigned)(t + 1), red, hstage, segaL, nt);
  }
}

// ---------------- batched decoder over all 128 generated h2 states ----------------
__global__ __launch_bounds__(256) void k_dec(const u16* __restrict__ h2hist, const u16* __restrict__ Wd,
                                             const float* __restrict__ bdec, float* __restrict__ out) {
  int blk = blockIdx.x;
  int s = blk / 10, nt = blk - s * 10;
  const u16* x = h2hist + (size_t)(s + 1) * 32768;
  int w = threadIdx.x >> 6, l = threadIdx.x & 63, q = l >> 4, r = l & 15;
  f32x4 acc[2] = {};
  for (int ks = w; ks < 32; ks += 4) {
    const u16* xp = x + ks * 1024 + q * 256 + r * 8;
    short8 a0 = *(const short8*)(xp);
    short8 a1 = *(const short8*)(xp + 128);
    short8 bf = *(const short8*)(Wd + (((size_t)nt * 128 + ks * 4) << 7) + l * 8);
    acc[0] = __builtin_amdgcn_mfma_f32_16x16x32_bf16(a0, bf, acc[0], 0, 0, 0);
    acc[1] = __builtin_amdgcn_mfma_f32_16x16x32_bf16(a1, bf, acc[1], 0, 0, 0);
  }
  __shared__ float red[4][2][256];
#pragma unroll
  for (int mt = 0; mt < 2; ++mt)
#pragma unroll
    for (int i = 0; i < 4; ++i) red[w][mt][l * 4 + i] = acc[mt][i];
  __syncthreads();
  for (int pp = threadIdx.x; pp < 512; pp += 256) {
    int b = pp >> 4, fs = pp & 15;
    int mt = b >> 4, row = b & 15;
    int lidx = ((row >> 2) * 16 + fs) * 4 + (row & 3);
    int f = nt * 16 + fs;
    if (f < 132) {
      float v = red[0][mt][lidx] + red[1][mt][lidx] + red[2][mt][lidx] + red[3][mt][lidx] + bdec[f];
      out[(size_t)b * (128 * 132) + s * 132 + f] = v;
    }
  }
}

// ---------------- host ----------------
extern "C" void kernel_launch(void* const* d_in, const int* in_sizes, int n_in,
                              void* d_out, int out_size, void* d_ws, size_t ws_size,
                              hipStream_t stream) {
  unsigned char* blob = nullptr;
  hipGetSymbolAddress((void**)&blob, HIP_SYMBOL(g_blob));

  const float* iseq = (const float*)d_in[0];
  const float* Wih1 = (const float*)d_in[2];
  const float* Whh1 = (const float*)d_in[3];
  const float* bih1 = (const float*)d_in[4];
  const float* bhh1 = (const float*)d_in[5];
  const float* Wih2 = (const float*)d_in[6];
  const float* Whh2 = (const float*)d_in[7];
  const float* bih2 = (const float*)d_in[8];
  const float* bhh2 = (const float*)d_in[9];
  const float* Wih3 = (const float*)d_in[10];
  const float* Whh3 = (const float*)d_in[11];
  const float* bih3 = (const float*)d_in[12];
  const float* bhh3 = (const float*)d_in[13];
  const float* Wdec = (const float*)d_in[14];
  const float* bdec = (const float*)d_in[15];

  u16* tWHH1 = (u16*)(blob + OFF_WHH1);
  u16* tWIH2 = (u16*)(blob + OFF_WIH2);
  u16* tWHH2 = (u16*)(blob + OFF_WHH2);
  u16* tWIH3 = (u16*)(blob + OFF_WIH3);
  u16* tWHH3 = (u16*)(blob + OFF_WHH3);
  u16* tMCOMB = (u16*)(blob + OFF_MCOMB);
  u16* tWIH1 = (u16*)(blob + OFF_WIH1);
  u16* tWDECF = (u16*)(blob + OFF_WDECF);
  u16* tWDECB = (u16*)(blob + OFF_WDECB);
  u16* XPRIM = (u16*)(blob + OFF_XPRIM);
  u16* H2HIST = (u16*)(blob + OFF_H2HIST);
  float* BS1 = (float*)(blob + OFF_BS1);
  float* BS1G = (float*)(blob + OFF_BS1G);
  float* BS2 = (float*)(blob + OFF_BS2);
  float* BS3 = (float*)(blob + OFF_BS3);

  // prep
  k_zero<<<68, 256, 0, stream>>>((uint4*)(blob + OFF_ZEROH), (int)(ZERO_BYTES / 16));
  k_swizzle<<<2048, 256, 0, stream>>>(Whh1, tWHH1, 4096, 4096, 1024, 1024, 1024, 0, 1);
  k_swizzle<<<2048, 256, 0, stream>>>(Wih2, tWIH2, 4096, 4096, 1024, 1024, 1024, 0, 1);
  k_swizzle<<<2048, 256, 0, stream>>>(Whh2, tWHH2, 4096, 4096, 1024, 1024, 1024, 0, 1);
  k_swizzle<<<2048, 256, 0, stream>>>(Wih3, tWIH3, 4096, 4096, 1024, 1024, 1024, 0, 1);
  k_swizzle<<<2048, 256, 0, stream>>>(Whh3, tWHH3, 4096, 4096, 1024, 1024, 1024, 0, 1);
  k_swizzle<<<2048, 256, 0, stream>>>(Wih1, tWIH1, 4096, 4096, 160, 132, 132, 0, 1);
  k_swizzle<<<512, 256, 0, stream>>>(Wdec, tWDECF, 160, 132, 1024, 1024, 1024, 0, 0);
  k_swizzle<<<512, 256, 0, stream>>>(Wdec, tWDECB, 1024, 1024, 160, 132, 1024, 1, 0);
  k_xprim<<<1280, 256, 0, stream>>>(iseq, XPRIM);
  k_bias<<<16, 256, 0, stream>>>(bih1, bhh1, bih2, bhh2, bih3, bhh3, Wih1, bdec, BS1, BS1G, BS2, BS3);
  k_mcomb<<<4096, 256, 0, stream>>>(tWIH1, tWDECB, tMCOMB);

  // persistent RNN
  {
    void* args[] = { (void*)&blob };
    hipError_t ce = hipLaunchCooperativeKernel((void*)k_rnn, dim3(256), dim3(512), args, 0, stream);
    if (ce != hipSuccess) {
      k_rnn<<<dim3(256), dim3(512), 0, stream>>>(blob);
    }
  }

  // batched decoder -> d_out fp32 [32][128][132]
  k_dec<<<1280, 256, 0, stream>>>(H2HIST, tWDECF, bdec, (float*)d_out);
}